// Round 2
// baseline (473.856 us; speedup 1.0000x reference)
//
#include <hip/hip_runtime.h>

#define NPTS 131072
#define MNBR 34
#define KP 15
#define CIN 32
#define COUT 64
#define INV_INFL 25.0f          // 1 / POINT_INFLUENCE(0.04)
#define BN_EPS 1e-5f
#define NEG_SLOPE 0.2f
#define PPB 32                  // points per block

typedef unsigned short u16;
typedef unsigned int u32;
typedef short short8 __attribute__((ext_vector_type(8)));   // 8 bf16 in 4 VGPRs
typedef float f32x4 __attribute__((ext_vector_type(4)));

static __device__ __forceinline__ u16 f2bf(float f) {
    u32 x = __float_as_uint(f);
    x += 0x7fffu + ((x >> 16) & 1u);   // round-to-nearest-even
    return (u16)(x >> 16);
}

// W[480][64] f32 -> WT[64][480] bf16 (B-fragment friendly: row d, contiguous k)
__global__ __launch_bounds__(256) void wt_kernel(const float* __restrict__ Wg,
                                                 u16* __restrict__ WT) {
    int tid = blockIdx.x * 256 + threadIdx.x;    // 30720 total
    int i = tid >> 6;                            // row of W (k*32+c), coalesced read
    int d = tid & 63;
    WT[d * 480 + i] = f2bf(Wg[tid]);
}

__global__ __launch_bounds__(256) void kpconv_conv(
    const float* __restrict__ xyz, const float* __restrict__ feats,
    const int* __restrict__ nbr, const u16* __restrict__ WT,
    const float* __restrict__ kpts, float* __restrict__ out)
{
    // wf: 32 points x 512 bf16 (480 used + pad), row = 1024 B = 64 16B-units.
    // unit u of row r stored at physical unit (u ^ (r&7)) -> b128 reads/writes
    // land 8 lanes per 4-bank group (the wave64 b128 optimum).
    __shared__ u32 wf[PPB * 256];     // 32 KiB

    const int tid  = threadIdx.x;
    const int lane = tid & 63;
    const int wave = tid >> 6;
    const int kk = lane >> 2;         // kernel point 0..15 (15 = pad)
    const int cg = lane & 3;          // channel group (8 ch each)

    float kpx = 0.f, kpy = 0.f, kpz = 0.f;
    if (kk < KP) {
        kpx = kpts[3 * kk + 0];
        kpy = kpts[3 * kk + 1];
        kpz = kpts[3 * kk + 2];
    }

    // ---------------- Phase A: wf[point][k*32+c] = sum_m w(m,k) * f[m][c]
    for (int p = 0; p < 8; ++p) {
        const int row = wave * 8 + p;                // point within block
        const int n = blockIdx.x * PPB + row;
        const float qx = xyz[3 * n + 0];
        const float qy = xyz[3 * n + 1];
        const float qz = xyz[3 * n + 2];

        int iiv = 0;
        float nxv = 1e6f, nyv = 1e6f, nzv = 1e6f;    // shadow -> w = 0 (finite!)
        if (lane < MNBR) {
            int ii = nbr[n * MNBR + lane];
            if ((unsigned)ii < (unsigned)NPTS) {
                iiv = ii;
                nxv = xyz[3 * ii + 0] - qx;
                nyv = xyz[3 * ii + 1] - qy;
                nzv = xyz[3 * ii + 2] - qz;
            }
        }

        float acc[8] = {0.f,0.f,0.f,0.f,0.f,0.f,0.f,0.f};
        for (int m = 0; m < MNBR; ++m) {
            int im  = __builtin_amdgcn_readlane(iiv, m);
            float bx = __uint_as_float(__builtin_amdgcn_readlane(__float_as_uint(nxv), m));
            float by = __uint_as_float(__builtin_amdgcn_readlane(__float_as_uint(nyv), m));
            float bz = __uint_as_float(__builtin_amdgcn_readlane(__float_as_uint(nzv), m));
            float dx = bx - kpx, dy = by - kpy, dz = bz - kpz;
            float dist = sqrtf(fmaf(dx, dx, fmaf(dy, dy, dz * dz)));
            float w = fmaxf(0.f, fmaf(dist, -INV_INFL, 1.f));
            const float4* fp = (const float4*)(feats + (size_t)im * CIN + cg * 8);
            float4 f0 = fp[0], f1 = fp[1];
            acc[0] = fmaf(w, f0.x, acc[0]); acc[1] = fmaf(w, f0.y, acc[1]);
            acc[2] = fmaf(w, f0.z, acc[2]); acc[3] = fmaf(w, f0.w, acc[3]);
            acc[4] = fmaf(w, f1.x, acc[4]); acc[5] = fmaf(w, f1.y, acc[5]);
            acc[6] = fmaf(w, f1.z, acc[6]); acc[7] = fmaf(w, f1.w, acc[7]);
        }

        // pack 8 f32 -> 8 bf16, one swizzled b128 write; kk==15 lands in units
        // 60..63 (pad, never read by phase B)
        uint4 pk;
        pk.x = (u32)f2bf(acc[0]) | ((u32)f2bf(acc[1]) << 16);
        pk.y = (u32)f2bf(acc[2]) | ((u32)f2bf(acc[3]) << 16);
        pk.z = (u32)f2bf(acc[4]) | ((u32)f2bf(acc[5]) << 16);
        pk.w = (u32)f2bf(acc[6]) | ((u32)f2bf(acc[7]) << 16);
        const int u = kk * 4 + cg;
        *((uint4*)&wf[row * 256 + ((u ^ (row & 7)) << 2)]) = pk;
    }
    __syncthreads();

    // ---------------- Phase B: OUT[32x64] = wf[32x480] @ W[480x64] via MFMA
    // A-frag: A[m=lane&15][k=(lane>>4)*8+j]  (m = point-in-tile, k = 480-dim)
    // B-frag: B[k=(lane>>4)*8+j][n=lane&15]  from WT[d][k] (contiguous in k)
    // C/D:    col=lane&15, row=(lane>>4)*4+reg  (m89-verified)
    const int t = lane & 15;
    const int q = lane >> 4;
    f32x4 acc0 = {0.f, 0.f, 0.f, 0.f};
    f32x4 acc1 = {0.f, 0.f, 0.f, 0.f};
    const u16* wtp = WT + (wave * 16 + t) * 480 + q * 8;
    const int row0 = t, row1 = 16 + t;
    #pragma unroll
    for (int ks = 0; ks < KP; ++ks) {
        short8 b = *(const short8*)(wtp + ks * 32);
        const int u = ks * 4 + q;
        short8 a0 = *(const short8*)&wf[row0 * 256 + ((u ^ (row0 & 7)) << 2)];
        short8 a1 = *(const short8*)&wf[row1 * 256 + ((u ^ (row1 & 7)) << 2)];
        acc0 = __builtin_amdgcn_mfma_f32_16x16x32_bf16(a0, b, acc0, 0, 0, 0);
        acc1 = __builtin_amdgcn_mfma_f32_16x16x32_bf16(a1, b, acc1, 0, 0, 0);
    }
    const int base = blockIdx.x * PPB;
    const int col = wave * 16 + t;
    #pragma unroll
    for (int r = 0; r < 4; ++r) {
        out[(base +      q * 4 + r) * COUT + col] = acc0[r];
        out[(base + 16 + q * 4 + r) * COUT + col] = acc1[r];
    }
}

__global__ void init_stats(float* __restrict__ stats) {
    stats[threadIdx.x] = 0.f;     // <<<1,128>>>: sum[64] + sumsq[64]
}

// stride 65536 is a multiple of 64 -> each thread sees one channel only
__global__ __launch_bounds__(256) void bn_stats(
    const float* __restrict__ out, float* __restrict__ stats)
{
    __shared__ float ss[256], sq[256];
    const int tid = threadIdx.x;
    const int g = blockIdx.x * 256 + tid;
    float s = 0.f, q2 = 0.f;
    for (int i = g; i < NPTS * COUT; i += 65536) {
        float v = out[i];
        s += v;
        q2 = fmaf(v, v, q2);
    }
    ss[tid] = s; sq[tid] = q2;
    __syncthreads();
    if (tid < 64) {
        s  = ss[tid] + ss[tid + 64] + ss[tid + 128] + ss[tid + 192];
        q2 = sq[tid] + sq[tid + 64] + sq[tid + 128] + sq[tid + 192];
        atomicAdd(&stats[tid], s);
        atomicAdd(&stats[64 + tid], q2);
    }
}

__global__ __launch_bounds__(256) void bn_apply(
    float* __restrict__ out, const float* __restrict__ stats,
    const float* __restrict__ gamma, const float* __restrict__ beta)
{
    __shared__ float sc[64], sh[64];
    const int tid = threadIdx.x;
    if (tid < 64) {
        float mean = stats[tid] * (1.0f / NPTS);
        float var  = stats[64 + tid] * (1.0f / NPTS) - mean * mean;
        float r = rsqrtf(var + BN_EPS);
        float g = gamma[tid] * r;
        sc[tid] = g;
        sh[tid] = beta[tid] - mean * g;
    }
    __syncthreads();
    const int gid = blockIdx.x * 256 + tid;      // 4 f32 per thread
    float4 v = ((const float4*)out)[gid];
    const int c0 = (gid * 4) & 63;               // c0 % 4 == 0, no wrap in quad
    float y0 = fmaf(v.x, sc[c0 + 0], sh[c0 + 0]);
    float y1 = fmaf(v.y, sc[c0 + 1], sh[c0 + 1]);
    float y2 = fmaf(v.z, sc[c0 + 2], sh[c0 + 2]);
    float y3 = fmaf(v.w, sc[c0 + 3], sh[c0 + 3]);
    float4 w;
    w.x = fmaxf(y0, NEG_SLOPE * y0);
    w.y = fmaxf(y1, NEG_SLOPE * y1);
    w.z = fmaxf(y2, NEG_SLOPE * y2);
    w.w = fmaxf(y3, NEG_SLOPE * y3);
    ((float4*)out)[gid] = w;
}

extern "C" void kernel_launch(void* const* d_in, const int* in_sizes, int n_in,
                              void* d_out, int out_size, void* d_ws, size_t ws_size,
                              hipStream_t stream) {
    (void)in_sizes; (void)n_in; (void)out_size; (void)ws_size;
    const float* xyz   = (const float*)d_in[0];
    const float* feats = (const float*)d_in[1];
    const int*   nbr   = (const int*)d_in[2];
    const float* Wg    = (const float*)d_in[3];
    const float* kpts  = (const float*)d_in[4];
    const float* gamma = (const float*)d_in[5];
    const float* beta  = (const float*)d_in[6];
    float* out   = (float*)d_out;
    float* stats = (float*)d_ws;
    u16*   WT    = (u16*)((char*)d_ws + 1024);   // 61440 B bf16 W-transpose

    init_stats<<<dim3(1), dim3(128), 0, stream>>>(stats);
    wt_kernel<<<dim3(120), dim3(256), 0, stream>>>(Wg, WT);
    kpconv_conv<<<dim3(NPTS / PPB), dim3(256), 0, stream>>>(xyz, feats, nbr, WT, kpts, out);
    bn_stats<<<dim3(256), dim3(256), 0, stream>>>(out, stats);
    bn_apply<<<dim3((NPTS * COUT) / (256 * 4)), dim3(256), 0, stream>>>(out, stats, gamma, beta);
}

// Round 3
// 237.319 us; speedup vs baseline: 1.9967x; 1.9967x over previous
//
#include <hip/hip_runtime.h>

#define NPTS 131072
#define MNBR 34
#define KP 15
#define CIN 32
#define COUT 64
#define INV_INFL 25.0f          // 1 / POINT_INFLUENCE(0.04)
#define BN_EPS 1e-5f
#define NEG_SLOPE 0.2f
#define PPB 32                  // points per block
#define NBLK (NPTS / PPB)       // 4096 conv blocks
#define RS 20                   // nbf row stride in dwords (64B data + 16B pad, b128-aligned)

typedef unsigned short u16;
typedef unsigned int u32;
typedef short short8 __attribute__((ext_vector_type(8)));   // 8 bf16 (4 VGPRs)
typedef float f32x4 __attribute__((ext_vector_type(4)));

static __device__ __forceinline__ u16 f2bf(float f) {       // RNE
    u32 x = __float_as_uint(f);
    x += 0x7fffu + ((x >> 16) & 1u);
    return (u16)(x >> 16);
}
static __device__ __forceinline__ u32 pk2bf(float lo, float hi) {  // round-half-up pack
    u32 a = __float_as_uint(lo) + 0x8000u;
    u32 b = __float_as_uint(hi) + 0x8000u;
    return (a >> 16) | (b & 0xffff0000u);
}

// ws layout (bytes)
#define WS_WT   0u              // u16[64*480]   = 61440
#define WS_SCSH 65536u          // f32[128]      (scale[64] | shift[64])
#define WS_SP   131072u         // f32[64*4096]  = 1 MB  per-block sums
#define WS_QP   1179648u        // f32[64*4096]  = 1 MB  per-block sumsq
#define WS_FB   2228224u        // u16[(NPTS+1)*32] = 8388672  bf16 feats + zero shadow row

// one-shot prep: WT[d][k*32+c] bf16 transpose of W, FB bf16 feature table (+ zero shadow row)
__global__ __launch_bounds__(256) void prep(const float* __restrict__ Wg,
                                            const float* __restrict__ feats,
                                            u16* __restrict__ WT, u32* __restrict__ FBu) {
    int b = blockIdx.x;
    if (b < 120) {
        int tid2 = b * 256 + threadIdx.x;        // < 30720
        int i = tid2 >> 6, d = tid2 & 63;        // i = k*32+c (coalesced read)
        WT[d * 480 + i] = f2bf(Wg[tid2]);
    } else {
        int g = (b - 120) * 256 + threadIdx.x;   // u32 index into FB
        if (g < ((NPTS + 1) * CIN) / 2) {
            int e = g * 2;
            u32 v = 0;
            if (e < NPTS * CIN)
                v = (u32)f2bf(feats[e]) | ((u32)f2bf(feats[e + 1]) << 16);
            FBu[g] = v;                          // row NPTS -> zeros (shadow)
        }
    }
}

__global__ __launch_bounds__(256) void kpconv_conv(
    const float* __restrict__ xyz, const int* __restrict__ nbr,
    const u16* __restrict__ FB, const u16* __restrict__ WT,
    const float* __restrict__ kpts, float* __restrict__ out,
    float* __restrict__ Sp, float* __restrict__ Qp)
{
    // wf: 32 rows x 512 bf16, 16B-unit u of row r at phys (u ^ (r&7))  [round-2 layout, unchanged]
    __shared__ u32 wf[PPB * 256];          // 32 KB
    __shared__ u32 nbf[4][64 * RS];        // 20 KB: per-wave neighbor-feature rows (bf16 pairs)
    __shared__ u16 wk[4][16 * 64];         // 8 KB:  per-wave w[k][m], 8-u16 units XOR-swizzled by k

    const int tid = threadIdx.x, lane = tid & 63, wave = tid >> 6;
    const int q = lane >> 4, t = lane & 15;

    // kernel points -> uniform regs (SGPRs); k=15 sentinel -> w row 15 == 0
    float kx[16], ky[16], kz[16];
    #pragma unroll
    for (int k = 0; k < KP; ++k) {
        kx[k] = kpts[3 * k]; ky[k] = kpts[3 * k + 1]; kz[k] = kpts[3 * k + 2];
    }
    kx[15] = 1e6f; ky[15] = 1e6f; kz[15] = 1e6f;

    u32* nb = nbf[wave];
    u16* wl = wk[wave];

    for (int p = 0; p < 8; ++p) {
        const int row = wave * 8 + p;                // point-row within block
        const int n = blockIdx.x * PPB + row;
        const float qx = xyz[3 * n], qy = xyz[3 * n + 1], qz = xyz[3 * n + 2];

        int ii = NPTS;                               // lanes >= MNBR: shadow row (zeros, w=0)
        if (lane < MNBR) ii = nbr[n * MNBR + lane];
        if ((unsigned)ii > (unsigned)NPTS) ii = NPTS;
        const int il = ii < NPTS ? ii : 0;           // clamped for xyz read
        float ox = xyz[3 * il] - qx, oy = xyz[3 * il + 1] - qy, oz = xyz[3 * il + 2] - qz;
        if (ii >= NPTS) { ox = 1e6f; oy = 0.f; oz = 0.f; }   // dist ~1e6 -> w = 0

        // stage neighbor feature row (64 B bf16) -> nbf[m=lane]
        const uint4* fr = (const uint4*)(FB + (size_t)ii * CIN);
        uint4 f0 = fr[0], f1 = fr[1], f2 = fr[2], f3 = fr[3];
        uint4* nrow = (uint4*)(nb + lane * RS);
        nrow[0] = f0; nrow[1] = f1; nrow[2] = f2; nrow[3] = f3;

        // w column for m=lane, all k; write bf16 into swizzled wk[k][m]
        #pragma unroll
        for (int k = 0; k < 16; ++k) {
            float dx = ox - kx[k], dy = oy - ky[k], dz = oz - kz[k];
            float d = __builtin_amdgcn_sqrtf(fmaf(dx, dx, fmaf(dy, dy, dz * dz)));
            float w = fmaxf(0.f, fmaf(d, -INV_INFL, 1.f));
            int unit = (lane >> 3) ^ (k & 7);
            wl[k * 64 + unit * 8 + (lane & 7)] = (u16)((__float_as_uint(w) + 0x8000u) >> 16);
        }
        __asm__ volatile("s_waitcnt lgkmcnt(0)" ::: "memory");

        // A-frags (w): lane holds A[k=t][m=32s+8q+j] -> single b128 per K-step
        short8 a0 = *(const short8*)&wl[t * 64 + (((0 * 4 + q) ^ (t & 7)) << 3)];
        short8 a1 = *(const short8*)&wl[t * 64 + (((1 * 4 + q) ^ (t & 7)) << 3)];

        // B-frags (nb_f): dword (m, c-word t) feeds BOTH tiles (even ch = lo, odd = hi)
        u32 r0[8], r1[8];
        #pragma unroll
        for (int j = 0; j < 8; ++j) {
            r0[j] = nb[(8 * q + j) * RS + t];
            r1[j] = nb[(8 * q + j + 32) * RS + t];
        }
        union { short8 v; u32 d[4]; } e0, o0, e1, o1;
        #pragma unroll
        for (int i2 = 0; i2 < 4; ++i2) {
            u32 a = r0[2 * i2], b = r0[2 * i2 + 1];
            e0.d[i2] = (a & 0xffffu) | (b << 16);
            o0.d[i2] = (a >> 16) | (b & 0xffff0000u);
            a = r1[2 * i2]; b = r1[2 * i2 + 1];
            e1.d[i2] = (a & 0xffffu) | (b << 16);
            o1.d[i2] = (a >> 16) | (b & 0xffff0000u);
        }

        // wf[k-rows x 32ch] for this point: tile0 = even channels, tile1 = odd
        f32x4 c0 = {0.f, 0.f, 0.f, 0.f}, c1 = {0.f, 0.f, 0.f, 0.f};
        c0 = __builtin_amdgcn_mfma_f32_16x16x32_bf16(a0, e0.v, c0, 0, 0, 0);
        c0 = __builtin_amdgcn_mfma_f32_16x16x32_bf16(a1, e1.v, c0, 0, 0, 0);
        c1 = __builtin_amdgcn_mfma_f32_16x16x32_bf16(a0, o0.v, c1, 0, 0, 0);
        c1 = __builtin_amdgcn_mfma_f32_16x16x32_bf16(a1, o1.v, c1, 0, 0, 0);

        // D: lane holds col=t, rows ko=q*4+r -> pack (ch 2t, 2t+1) u32 into swizzled wf tile
        #pragma unroll
        for (int r = 0; r < 4; ++r) {
            int ko = q * 4 + r;
            u32 pk = pk2bf(c0[r], c1[r]);
            int unit = ko * 4 + (t >> 2);
            wf[row * 256 + ((unit ^ (row & 7)) << 2) + (t & 3)] = pk;
        }
        __asm__ volatile("s_waitcnt lgkmcnt(0)" ::: "memory");
    }
    __syncthreads();

    // -------- Phase B (round-2 verified): OUT[32x64] = wf[32x480] @ W[480x64]
    const int wcol = wave * 16 + t;
    f32x4 acc0 = {0.f, 0.f, 0.f, 0.f}, acc1 = {0.f, 0.f, 0.f, 0.f};
    const u16* wtp = WT + wcol * 480 + q * 8;
    const int row0 = t, row1 = 16 + t;
    #pragma unroll
    for (int ks = 0; ks < KP; ++ks) {
        short8 b = *(const short8*)(wtp + ks * 32);
        const int u = ks * 4 + q;
        short8 a0 = *(const short8*)&wf[row0 * 256 + ((u ^ (row0 & 7)) << 2)];
        short8 a1 = *(const short8*)&wf[row1 * 256 + ((u ^ (row1 & 7)) << 2)];
        acc0 = __builtin_amdgcn_mfma_f32_16x16x32_bf16(a0, b, acc0, 0, 0, 0);
        acc1 = __builtin_amdgcn_mfma_f32_16x16x32_bf16(a1, b, acc1, 0, 0, 0);
    }
    const int base = blockIdx.x * PPB;
    float s = 0.f, q2 = 0.f;
    #pragma unroll
    for (int r = 0; r < 4; ++r) {
        float v0 = acc0[r], v1 = acc1[r];
        out[(base +      q * 4 + r) * COUT + wcol] = v0;
        out[(base + 16 + q * 4 + r) * COUT + wcol] = v1;
        s += v0 + v1;
        q2 = fmaf(v0, v0, q2); q2 = fmaf(v1, v1, q2);
    }
    // reduce over q (lanes t, t+16, t+32, t+48 share channel wcol)
    s  += __shfl_xor(s, 16, 64);  s  += __shfl_xor(s, 32, 64);
    q2 += __shfl_xor(q2, 16, 64); q2 += __shfl_xor(q2, 32, 64);
    if (q == 0) {
        Sp[wcol * NBLK + blockIdx.x] = s;
        Qp[wcol * NBLK + blockIdx.x] = q2;
    }
}

// 64 blocks: block = channel; reduce per-block partials -> scale/shift
__global__ __launch_bounds__(256) void bn_reduce(
    const float* __restrict__ Sp, const float* __restrict__ Qp,
    const float* __restrict__ gamma, const float* __restrict__ beta,
    float* __restrict__ scsh)
{
    const int ch = blockIdx.x;
    const float4* S4 = (const float4*)(Sp + ch * NBLK);
    const float4* Q4 = (const float4*)(Qp + ch * NBLK);
    float s = 0.f, qq = 0.f;
    #pragma unroll
    for (int r = 0; r < NBLK / 4 / 256; ++r) {           // 4 iters
        float4 a = S4[threadIdx.x + 256 * r]; s  += a.x + a.y + a.z + a.w;
        float4 b = Q4[threadIdx.x + 256 * r]; qq += b.x + b.y + b.z + b.w;
    }
    #pragma unroll
    for (int off = 1; off < 64; off <<= 1) {
        s += __shfl_xor(s, off, 64); qq += __shfl_xor(qq, off, 64);
    }
    __shared__ float red[8];
    const int w = threadIdx.x >> 6;
    if ((threadIdx.x & 63) == 0) { red[w * 2] = s; red[w * 2 + 1] = qq; }
    __syncthreads();
    if (threadIdx.x == 0) {
        s  = red[0] + red[2] + red[4] + red[6];
        qq = red[1] + red[3] + red[5] + red[7];
        float mean = s * (1.0f / NPTS);
        float var  = qq * (1.0f / NPTS) - mean * mean;
        float sc = gamma[ch] * rsqrtf(var + BN_EPS);
        scsh[ch] = sc;
        scsh[64 + ch] = beta[ch] - mean * sc;
    }
}

__global__ __launch_bounds__(256) void bn_apply(
    float* __restrict__ out, const float* __restrict__ scsh)
{
    __shared__ float sc[64], sh[64];
    const int tid = threadIdx.x;
    if (tid < 64) { sc[tid] = scsh[tid]; sh[tid] = scsh[64 + tid]; }
    __syncthreads();
    const int gid = blockIdx.x * 256 + tid;          // 4 f32 per thread
    float4 v = ((const float4*)out)[gid];
    const int c0 = (gid * 4) & 63;
    float y0 = fmaf(v.x, sc[c0 + 0], sh[c0 + 0]);
    float y1 = fmaf(v.y, sc[c0 + 1], sh[c0 + 1]);
    float y2 = fmaf(v.z, sc[c0 + 2], sh[c0 + 2]);
    float y3 = fmaf(v.w, sc[c0 + 3], sh[c0 + 3]);
    float4 w;
    w.x = fmaxf(y0, NEG_SLOPE * y0);
    w.y = fmaxf(y1, NEG_SLOPE * y1);
    w.z = fmaxf(y2, NEG_SLOPE * y2);
    w.w = fmaxf(y3, NEG_SLOPE * y3);
    ((float4*)out)[gid] = w;
}

extern "C" void kernel_launch(void* const* d_in, const int* in_sizes, int n_in,
                              void* d_out, int out_size, void* d_ws, size_t ws_size,
                              hipStream_t stream) {
    (void)in_sizes; (void)n_in; (void)out_size; (void)ws_size;
    const float* xyz   = (const float*)d_in[0];
    const float* feats = (const float*)d_in[1];
    const int*   nbr   = (const int*)d_in[2];
    const float* Wg    = (const float*)d_in[3];
    const float* kpts  = (const float*)d_in[4];
    const float* gamma = (const float*)d_in[5];
    const float* beta  = (const float*)d_in[6];
    float* out = (float*)d_out;
    char* ws = (char*)d_ws;
    u16*   WT   = (u16*)(ws + WS_WT);
    float* scsh = (float*)(ws + WS_SCSH);
    float* Sp   = (float*)(ws + WS_SP);
    float* Qp   = (float*)(ws + WS_QP);
    u16*   FB   = (u16*)(ws + WS_FB);

    prep<<<dim3(120 + 8193), dim3(256), 0, stream>>>(Wg, feats, WT, (u32*)FB);
    kpconv_conv<<<dim3(NBLK), dim3(256), 0, stream>>>(xyz, nbr, FB, WT, kpts, out, Sp, Qp);
    bn_reduce<<<dim3(64), dim3(256), 0, stream>>>(Sp, Qp, gamma, beta, scsh);
    bn_apply<<<dim3((NPTS * COUT) / (256 * 4)), dim3(256), 0, stream>>>(out, scsh);
}